// Round 5
// baseline (330.423 us; speedup 1.0000x reference)
//
#include <hip/hip_runtime.h>

// Problem constants (reference: BATCH=64, NUM_SPEC=8, VOCAB=128000)
constexpr int BATCH    = 64;
constexpr int NUM_SPEC = 8;
constexpr int VOCAB    = 128000;
constexpr int ROWS     = BATCH * NUM_SPEC;   // 512 argmax rows
constexpr int T1       = 1024;               // threads per argmax block (16 waves)

typedef float vfloat4 __attribute__((ext_vector_type(4)));

// R5 theory: sc0 sc1 (system-scope) loads take an uncached coherence path that
// caps per-CU streaming BW (~6.8 GB/s/CU observed -> 1.75 TB/s chip-wide, 3.5x
// off the 6.3 TB/s roofline for a 262 MB pure stream). Device-scope
// non-temporal ('nt' only) keeps the full-width vector path while staying
// non-allocating, so it still avoids mass eviction of the 256 MB of dirty
// 0xAA ws-poison lines (the R2 writeback storm).
// saddr form: uniform row base lives in an SGPR pair, per-load address is a
// 32-bit VGPR byte offset -> big VGPR saving, lets 8 loads stay in flight
// under the 64-VGPR cap of __launch_bounds__(1024, 8).
__device__ __forceinline__ void nt_load(vfloat4& dst, int voff, const float* sbase) {
    asm volatile("global_load_dwordx4 %0, %1, %2 nt"
                 : "=v"(dst) : "v"(voff), "s"(sbase));
}
// Counted-vmcnt pipeline waits. Loads are invisible to the compiler's vmcnt
// tracking, so each wait ties the registers of the group being consumed
// ("+v") to create the data dependence. With 8 loads outstanding,
// vmcnt(4) == "the oldest group of 4 is complete".
__device__ __forceinline__ void wait_vm4(vfloat4& a, vfloat4& b, vfloat4& c, vfloat4& d) {
    asm volatile("s_waitcnt vmcnt(4)" : "+v"(a), "+v"(b), "+v"(c), "+v"(d));
}
__device__ __forceinline__ void wait_vm0(vfloat4& a, vfloat4& b, vfloat4& c, vfloat4& d) {
    asm volatile("s_waitcnt vmcnt(0)" : "+v"(a), "+v"(b), "+v"(c), "+v"(d));
}

// Per-row argmax over vocab, first-index tie-break (matches jnp.argmax).
// One 1024-thread block per row: 512 blocks -> 2 blocks/CU -> 32 waves/CU.
// Software pipeline: two 4-load groups (8 x dwordx4 = 8 KB/wave) permanently
// in flight; main body never drains vmcnt to 0.
__global__ __launch_bounds__(T1, 8) void rs_argmax(const float* __restrict__ logits,
                                                   int* __restrict__ targets) {
    const int row = blockIdx.x;  // 0..511
    const int tid = threadIdx.x;
    const float* __restrict__ basef = logits + (size_t)row * VOCAB;

    // Byte offsets for the 4 strided loads of a group (vec stride 1024 = 16 KB).
    const int voff0 = tid << 4;
    const int voff1 = voff0 + 16384;
    const int voff2 = voff0 + 32768;
    const int voff3 = voff0 + 49152;
    // Tail group (j=7): k=3 exists only for tid < 256 (tid+31744 < 32000).
    // Clamp the address back to the group's k=0 slot for tid >= 256 (value-
    // safe duplicate, update predicated off) so the load stays in-bounds.
    const bool has4  = (tid < 256);
    const int voff3t = has4 ? voff3 : voff0;

    float best = -__builtin_inff();
    int   bidx = VOCAB;  // sentinel

    auto upd = [&](const vfloat4 v, const int vecidx) {
        const int base = vecidx << 2;
        if (v.x > best) { best = v.x; bidx = base;     }
        if (v.y > best) { best = v.y; bidx = base + 1; }
        if (v.z > best) { best = v.z; bidx = base + 2; }
        if (v.w > best) { best = v.w; bidx = base + 3; }
    };
    // Per-thread consume order is strictly increasing in vec index (group j
    // ascending, k ascending), so '>' keeps the lowest index on ties.
    auto consume = [&](const int j, const vfloat4 v0, const vfloat4 v1,
                       const vfloat4 v2, const vfloat4 v3) {
        const int jb = tid + j * 4096;
        upd(v0, jb);
        upd(v1, jb + 1024);
        upd(v2, jb + 2048);
        upd(v3, jb + 3072);
    };

    vfloat4 A0, A1, A2, A3, B0, B1, B2, B3;

    // Prologue: groups 0 (A) and 1 (B) in flight.
    nt_load(A0, voff0, basef);
    nt_load(A1, voff1, basef);
    nt_load(A2, voff2, basef);
    nt_load(A3, voff3, basef);
    nt_load(B0, voff0, basef + 1 * 16384);
    nt_load(B1, voff1, basef + 1 * 16384);
    nt_load(B2, voff2, basef + 1 * 16384);
    nt_load(B3, voff3, basef + 1 * 16384);

    // Steady state: wait oldest group (vmcnt(4)), consume it, refill its regs.
    wait_vm4(A0, A1, A2, A3);  consume(0, A0, A1, A2, A3);
    nt_load(A0, voff0, basef + 2 * 16384);
    nt_load(A1, voff1, basef + 2 * 16384);
    nt_load(A2, voff2, basef + 2 * 16384);
    nt_load(A3, voff3, basef + 2 * 16384);

    wait_vm4(B0, B1, B2, B3);  consume(1, B0, B1, B2, B3);
    nt_load(B0, voff0, basef + 3 * 16384);
    nt_load(B1, voff1, basef + 3 * 16384);
    nt_load(B2, voff2, basef + 3 * 16384);
    nt_load(B3, voff3, basef + 3 * 16384);

    wait_vm4(A0, A1, A2, A3);  consume(2, A0, A1, A2, A3);
    nt_load(A0, voff0, basef + 4 * 16384);
    nt_load(A1, voff1, basef + 4 * 16384);
    nt_load(A2, voff2, basef + 4 * 16384);
    nt_load(A3, voff3, basef + 4 * 16384);

    wait_vm4(B0, B1, B2, B3);  consume(3, B0, B1, B2, B3);
    nt_load(B0, voff0, basef + 5 * 16384);
    nt_load(B1, voff1, basef + 5 * 16384);
    nt_load(B2, voff2, basef + 5 * 16384);
    nt_load(B3, voff3, basef + 5 * 16384);

    wait_vm4(A0, A1, A2, A3);  consume(4, A0, A1, A2, A3);
    nt_load(A0, voff0, basef + 6 * 16384);
    nt_load(A1, voff1, basef + 6 * 16384);
    nt_load(A2, voff2, basef + 6 * 16384);
    nt_load(A3, voff3, basef + 6 * 16384);

    wait_vm4(B0, B1, B2, B3);  consume(5, B0, B1, B2, B3);
    nt_load(B0, voff0,  basef + 7 * 16384);   // tail group j=7
    nt_load(B1, voff1,  basef + 7 * 16384);
    nt_load(B2, voff2,  basef + 7 * 16384);
    nt_load(B3, voff3t, basef + 7 * 16384);

    wait_vm4(A0, A1, A2, A3);  consume(6, A0, A1, A2, A3);

    // Epilogue: drain last group.
    wait_vm0(B0, B1, B2, B3);
    {
        const int jb = tid + 7 * 4096;
        upd(B0, jb);
        upd(B1, jb + 1024);
        upd(B2, jb + 2048);
        if (has4) upd(B3, jb + 3072);
    }

    // 64-lane wave reduction, lowest-index tie-break.
    #pragma unroll
    for (int off = 32; off > 0; off >>= 1) {
        const float ov = __shfl_down(best, off, 64);
        const int   oi = __shfl_down(bidx, off, 64);
        if (ov > best || (ov == best && oi < bidx)) { best = ov; bidx = oi; }
    }

    __shared__ float sval[T1 / 64];
    __shared__ int   sidx[T1 / 64];
    const int lane = tid & 63;
    const int wave = tid >> 6;
    if (lane == 0) { sval[wave] = best; sidx[wave] = bidx; }
    __syncthreads();

    if (tid == 0) {
        best = sval[0]; bidx = sidx[0];
        #pragma unroll
        for (int w = 1; w < T1 / 64; ++w) {
            if (sval[w] > best || (sval[w] == best && sidx[w] < bidx)) {
                best = sval[w]; bidx = sidx[w];
            }
        }
        targets[row] = bidx;
    }
}

// Per-batch rejection-sampling logic. One thread per batch row.
// Output layout (int32, concatenated flat in return order):
//   [0,   576)  output_token_ids [64,9]
//   [576, 640)  num_rejected_tokens [64]
//   [640, 704)  last_token_ids [64]
__global__ __launch_bounds__(64) void rs_finalize(const int* __restrict__ targets,
                                                  const int* __restrict__ draft,
                                                  const int* __restrict__ bonus,
                                                  int* __restrict__ out) {
    const int b = threadIdx.x;
    if (b >= BATCH) return;

    int tgt[NUM_SPEC];
    int L = 0;            // matched-prefix length
    bool prefix = true;
    #pragma unroll
    for (int s = 0; s < NUM_SPEC; ++s) {
        tgt[s] = targets[b * NUM_SPEC + s];
        const bool m = (draft[b * NUM_SPEC + s] == tgt[s]);
        prefix = prefix && m;
        if (prefix) ++L;
    }

    const bool all_acc = (L == NUM_SPEC);
    const int keep_cnt = all_acc ? NUM_SPEC : (L + 1);

    int* __restrict__ out_tok = out + b * (NUM_SPEC + 1);
    #pragma unroll
    for (int s = 0; s < NUM_SPEC; ++s) {
        out_tok[s] = (s < keep_cnt) ? tgt[s] : -1;
    }
    const int bonus_tok = bonus[b];
    out_tok[NUM_SPEC] = all_acc ? bonus_tok : -1;

    out[BATCH * (NUM_SPEC + 1) + b] = NUM_SPEC - L;                // num_rejected
    out[BATCH * (NUM_SPEC + 1) + BATCH + b] = all_acc ? bonus_tok  // last_token
                                                      : tgt[L];
}

extern "C" void kernel_launch(void* const* d_in, const int* in_sizes, int n_in,
                              void* d_out, int out_size, void* d_ws, size_t ws_size,
                              hipStream_t stream) {
    const float* logits = (const float*)d_in[0];  // [64, 8, 128000] fp32
    const int*   draft  = (const int*)d_in[1];    // [64, 8] int32
    const int*   bonus  = (const int*)d_in[2];    // [64, 1] int32
    int* out = (int*)d_out;                       // 704 int32
    int* targets = (int*)d_ws;                    // 512 int32 scratch

    rs_argmax<<<ROWS, T1, 0, stream>>>(logits, targets);
    rs_finalize<<<1, 64, 0, stream>>>(targets, draft, bonus, out);
}